// Round 14
// baseline (174.331 us; speedup 1.0000x reference)
//
#include <hip/hip_runtime.h>
#include <hip/hip_fp16.h>

#define NATOMS 768
#define NM1    767
#define NEDGE  (768*767)       // 589056
#define DIM    64
#define NC     50
#define GAPF   (5.0f/49.0f)
#define NIGAP  (-49.0f/5.0f)
#define G      512
#define STEPF  (5.0f/511.0f)
#define INVSTEP (511.0f/5.0f)
#define LN2F   0.693147180559945f

// ws layout (float offsets)
#define WS_H     0              // 768*64 f32
#define WS_NWA   49152          // 768*64 f16 ROW-MAJOR: nw[i*64+c]
#define WS_NWB   73728          // 768*64 f16 row-major
#define WS_HA    98304          // 768 f32 (+pad)
#define WS_DISTT 99328          // 768*768 f32
#define WS_TT    689152         // 4 tables * 512*64 __half2 = 131072 float slots

#define PIPE_FENCE() asm volatile("" ::: "memory")

__device__ __forceinline__ float softplus05(float x) {
    float bx = 0.5f * x;
    return (bx > 14.0f) ? x : 2.0f * __logf(1.0f + __expf(bx));
}
__device__ __forceinline__ int lane_bcast_i(int v, int l) {
    return __builtin_amdgcn_readlane(v, l);
}
__device__ __forceinline__ float lane_bcast_f(float v, int l) {
    return __uint_as_float((unsigned)__builtin_amdgcn_readlane((int)__float_as_uint(v), l));
}
__device__ __forceinline__ float2 pair2f(unsigned p) {
    __half2 h = *reinterpret_cast<__half2*>(&p);
    return __half22float2(h);
}

// ============ prologue: f16 tables + embed/nw0(row-major f16) + dist transpose ====
__global__ __launch_bounds__(256)
void k_pre(const int* __restrict__ types, const float* __restrict__ dist,
           const float* __restrict__ emb, const float* __restrict__ w1all,
           const float* __restrict__ pw1, const float* __restrict__ pb1,
           const float* __restrict__ pw2, const float* __restrict__ pb2,
           const float* __restrict__ row1, const float* __restrict__ rob1,
           float* __restrict__ ws) {
    __shared__ float s_t[4 * 64];
    __shared__ float s_tile[64][65];
    const int tid = threadIdx.x, widx = tid >> 6, c = tid & 63;
    float*  h     = ws + WS_H;
    __half* nwh   = (__half*)(ws + WS_NWA);
    float*  distT = ws + WS_DISTT;
    __half* TTh   = (__half*)(ws + WS_TT);
    const int b = blockIdx.x;

    if (b < 512) {
        const int w = b * 4 + widx, tbl = w >> 9, g = w & 511;
        const float d = g * STEPF;
        float val;
        if (tbl < 3) {
            const float* W1 = pw1 + tbl * NC * DIM;
            float t1 = pb1[tbl * DIM + c];
            for (int k = 0; k < NC; ++k) {
                float x = d - GAPF * (float)k;
                t1 = fmaf(__expf(NIGAP * x * x), W1[k * DIM + c], t1);
            }
            s_t[widx * 64 + c] = softplus05(t1);     // wave-local lockstep
            const float* W2 = pw2 + tbl * DIM * DIM;
            val = pb2[tbl * DIM + c];
            #pragma unroll 8
            for (int k = 0; k < DIM; ++k)
                val = fmaf(s_t[widx * 64 + k], W2[k * DIM + c], val);
        } else {
            val = rob1[c];
            for (int k = 0; k < NC; ++k) {
                float x = d - GAPF * (float)k;
                val = fmaf(__expf(NIGAP * x * x), row1[(2 + k) * DIM + c], val);
            }
        }
        // paired f16 layout: entry (g,c) holds (T[g][c], T[g+1][c]) as __half2
        __half* TTt = TTh + tbl * (G * DIM * 2);
        TTt[(g * DIM + c) * 2] = __float2half(val);
        if (g > 0) TTt[((g - 1) * DIM + c) * 2 + 1] = __float2half(val);
    } else if (b < 704) {
        const int i = (b - 512) * 4 + widx;
        float hv = emb[types[i] * DIM + c];
        h[i * DIM + c] = hv;
        s_t[widx * 64 + c] = hv;                     // wave-local
        float acc = 0.0f;
        #pragma unroll 8
        for (int k = 0; k < DIM; ++k)
            acc = fmaf(s_t[widx * 64 + k], w1all[k * DIM + c], acc);
        nwh[i * 64 + c] = __float2half(acc);         // row-major
    } else {
        // ---- coalesced tiled transpose: dist(i-major, edge order) -> distT[j][i]
        const int t = b - 704;                       // 144 tiles = 12 x 12
        const int I0 = (t / 12) * 64, J0 = (t % 12) * 64;
        #pragma unroll 4
        for (int r = 0; r < 16; ++r) {               // read rows of dist, coalesced in j
            const int i = I0 + widx * 16 + r;
            const int j = J0 + c;
            s_tile[widx * 16 + r][c] =
                (i == j) ? 0.0f : dist[i * NM1 + (j - (j > i))];
        }
        __syncthreads();
        #pragma unroll 4
        for (int r = 0; r < 16; ++r) {               // write rows of distT, coalesced in i
            const int j = J0 + widx * 16 + r;
            const int i = I0 + c;
            distT[j * NATOMS + i] = s_tile[c][widx * 16 + r];
        }
    }
}

// ============ conv layer: R12 edge loop + tail-v2 (all-wave redundant combine) =
// 768 blocks x 8 waves; wave widx covers sources [widx*96, widx*96+96).
// Tail: every wave combines partials itself (no wave-0 serial section); the
// next stage's k-slice inputs come from intra-wave readlane; ping-pong LDS
// buffers remove WAR barriers -> 4 syncthreads/layer (was 7), 0 serial stages.
__global__ __launch_bounds__(512)
void k_edgeupd(const __half2* __restrict__ TTl, const float* __restrict__ distT,
               const __half* __restrict__ nwin,
               const float* __restrict__ qw1, const float* __restrict__ qb1,
               const float* __restrict__ qw2, const float* __restrict__ qb2,
               float* __restrict__ h,
               const float* __restrict__ wnext, __half* __restrict__ nwout,
               const float* __restrict__ auw1, const float* __restrict__ aub1,
               const float* __restrict__ auw2, const float* __restrict__ aub2,
               float* __restrict__ ha, int last) {
    __shared__ float s_part[8][64];                  // ping
    __shared__ float s_pb[8][64];                    // pong
    const int tid = threadIdx.x, widx = tid >> 6, c = tid & 63;
    const int j = blockIdx.x;
    const int s0 = widx * 96;
    const int half = c >> 5, cl = c & 31;

    // prefetch tail operands early (all waves need them for redundant combine)
    float2 t0_pf = pair2f(((const unsigned*)TTl)[c]);
    float nwj_pf = __half2float(nwin[j * 64 + c]);
    float hj_pf  = h[j * DIM + c];

    const char* TTrow = (const char*)TTl + cl * 8;   // lane's 2-channel slot in a row
    float2 csum = make_float2(0.0f, 0.0f);
    { // ---- chunk A: sources s0 .. s0+63 (32 pairs); lane c holds (g,f) of s0+c
        float d = distT[j * NATOMS + s0 + c];
        float pos = d * INVSTEP;
        int g = (int)pos;
        g = (g < 0) ? 0 : ((g > 510) ? 510 : g);
        float f = pos - (float)g;
        int kx = g * 256;                            // byte offset of f16 row
        const char* nwrow = (const char*)nwin + s0 * 128 + half * 128 + cl * 4;
        for (int grp = 0; grp < 4; ++grp) {          // 4 groups of 8 pairs
            uint2 st[8]; unsigned sn[8];
            #pragma unroll
            for (int u = 0; u < 8; ++u) {            // stage: 16 independent loads
                const int t = grp * 8 + u;
                int kx0 = lane_bcast_i(kx, 2 * t);
                int kx1 = lane_bcast_i(kx, 2 * t + 1);
                int kxs = half ? kx1 : kx0;
                st[u] = *(const uint2*)(TTrow + kxs);
                sn[u] = *(const unsigned*)(nwrow + t * 256);
            }
            PIPE_FENCE();
            #pragma unroll
            for (int u = 0; u < 8; ++u) {            // consume
                const int t = grp * 8 + u;
                float f0 = lane_bcast_f(f, 2 * t);
                float f1 = lane_bcast_f(f, 2 * t + 1);
                float fs = half ? f1 : f0;
                float2 ta = pair2f(st[u].x);
                float2 tb = pair2f(st[u].y);
                float2 nwf = pair2f(sn[u]);
                float e0 = fmaf(fs, ta.y - ta.x, ta.x);
                float e1 = fmaf(fs, tb.y - tb.x, tb.x);
                csum.x = fmaf(e0, nwf.x, csum.x);
                csum.y = fmaf(e1, nwf.y, csum.y);
            }
        }
    }
    { // ---- chunk B: sources s0+64 .. s0+95 (16 pairs); lanes mirrored via c&31
        float d = distT[j * NATOMS + s0 + 64 + cl];
        float pos = d * INVSTEP;
        int g = (int)pos;
        g = (g < 0) ? 0 : ((g > 510) ? 510 : g);
        float f = pos - (float)g;
        int kx = g * 256;
        const char* nwrow = (const char*)nwin + (s0 + 64) * 128 + half * 128 + cl * 4;
        for (int grp = 0; grp < 2; ++grp) {          // 2 groups of 8 pairs
            uint2 st[8]; unsigned sn[8];
            #pragma unroll
            for (int u = 0; u < 8; ++u) {
                const int t = grp * 8 + u;
                int kx0 = lane_bcast_i(kx, 2 * t);
                int kx1 = lane_bcast_i(kx, 2 * t + 1);
                int kxs = half ? kx1 : kx0;
                st[u] = *(const uint2*)(TTrow + kxs);
                sn[u] = *(const unsigned*)(nwrow + t * 256);
            }
            PIPE_FENCE();
            #pragma unroll
            for (int u = 0; u < 8; ++u) {
                const int t = grp * 8 + u;
                float f0 = lane_bcast_f(f, 2 * t);
                float f1 = lane_bcast_f(f, 2 * t + 1);
                float fs = half ? f1 : f0;
                float2 ta = pair2f(st[u].x);
                float2 tb = pair2f(st[u].y);
                float2 nwf = pair2f(sn[u]);
                float e0 = fmaf(fs, ta.y - ta.x, ta.x);
                float e1 = fmaf(fs, tb.y - tb.x, tb.x);
                csum.x = fmaf(e0, nwf.x, csum.x);
                csum.y = fmaf(e1, nwf.y, csum.y);
            }
        }
    }
    // combine even/odd source halves and repack to channel-per-slot
    float2 tot2;
    tot2.x = csum.x + __shfl_xor(csum.x, 32, 64);
    tot2.y = csum.y + __shfl_xor(csum.y, 32, 64);
    if (half == 0) *(float2*)&s_part[widx][2 * cl] = tot2;
    __syncthreads();                                 // [1]

    const int k0 = widx * 8;
    // ---- A+B: redundant combine of edge partials, diag fix, k-slice of MLP1
    float tot = 0.0f;
    #pragma unroll
    for (int w8 = 0; w8 < 8; ++w8) tot += s_part[w8][c];
    tot -= t0_pf.x * nwj_pf;     // remove fake i==j term (e = T[0][c] exactly)
    float p = 0.0f;
    #pragma unroll
    for (int u = 0; u < 8; ++u)
        p = fmaf(lane_bcast_f(tot, k0 + u), qw1[(k0 + u) * DIM + c], p);
    s_pb[widx][c] = p;
    __syncthreads();                                 // [2]
    // ---- C: redundant combine of MLP1, softplus, k-slice of MLP2
    float t = qb1[c];
    #pragma unroll
    for (int w8 = 0; w8 < 8; ++w8) t += s_pb[w8][c];
    float sp = softplus05(t);
    p = 0.0f;
    #pragma unroll
    for (int u = 0; u < 8; ++u)
        p = fmaf(lane_bcast_f(sp, k0 + u), qw2[(k0 + u) * DIM + c], p);
    s_part[widx][c] = p;
    __syncthreads();                                 // [3]
    // ---- D: redundant combine of MLP2, h update, k-slice of next-nw / au head
    float o = qb2[c];
    #pragma unroll
    for (int w8 = 0; w8 < 8; ++w8) o += s_part[w8][c];
    float hn = hj_pf + o;
    if (widx == 0) h[j * DIM + c] = hn;
    {
        const float* W = last ? auw1 : wnext;
        p = 0.0f;
        #pragma unroll
        for (int u = 0; u < 8; ++u)
            p = fmaf(lane_bcast_f(hn, k0 + u), W[(k0 + u) * DIM + c], p);
        s_pb[widx][c] = p;
    }
    __syncthreads();                                 // [4]
    if (widx == 0) {
        if (!last) {
            float v = 0.0f;
            #pragma unroll
            for (int w8 = 0; w8 < 8; ++w8) v += s_pb[w8][c];
            nwout[j * 64 + c] = __float2half(v);     // row-major
        } else {
            float t2 = aub1[c];
            #pragma unroll
            for (int w8 = 0; w8 < 8; ++w8) t2 += s_pb[w8][c];
            t2 = ((t2 > 20.0f) ? t2 : __logf(1.0f + __expf(t2))) - LN2F;
            float v = t2 * auw2[c];
            #pragma unroll
            for (int s = 32; s > 0; s >>= 1) v += __shfl_down(v, s, 64);
            if (c == 0) ha[j] = v + aub2[0];
        }
    }
}

// ============ readout: FENCED staged loads; src/dst by exact magic division ====
__global__ __launch_bounds__(256)
void k_ro(const float* __restrict__ dist, const float* __restrict__ ha,
          const __half2* __restrict__ TTro,
          const float* __restrict__ row1, const float* __restrict__ row2,
          const float* __restrict__ rob2, float* __restrict__ out) {
    __shared__ float s_h[4][16 * 65];
    __shared__ float s_w2[128];
    const int tid = threadIdx.x, widx = tid >> 6, c = tid & 63;
    if (tid < 128) s_w2[tid] = row2[tid];
    __syncthreads();
    const int ebase = (blockIdx.x * 4 + widx) * 64;

    // lane c holds the params of edge ebase+c, in registers
    int kxv; float ff, fa, fb;
    {
        int eg = ebase + c;
        float d = dist[eg];
        float pos = d * INVSTEP;
        int kk = (int)pos;
        kk = (kk < 0) ? 0 : ((kk > 510) ? 510 : kk);
        kxv = kk * 256;
        ff = pos - (float)kk;
        // src = eg/767 (exact magic div), dst = r + (r>=src)
        unsigned i = (unsigned)(((unsigned long long)(unsigned)eg * 2867044662ull) >> 41);
        int r = eg - (int)i * 767;
        int jd = r + (r >= (int)i);
        fa = ha[i];
        fb = ha[jd];
    }
    const char* TTb2 = (const char*)TTro + c * 4;
    const float wa = row1[c], wb = row1[DIM + c];
    const int e2 = (c >> 1) & 15, p2 = c & 1, kh = c >> 5;
    const float bias2 = (kh == 0) ? rob2[p2] : 0.0f;
    float* sh = s_h[widx];
    #pragma unroll
    for (int ch = 0; ch < 4; ++ch) {
        #pragma unroll
        for (int half = 0; half < 2; ++half) {
            unsigned st[8];
            #pragma unroll
            for (int u = 0; u < 8; ++u) {            // stage: 8 independent row loads
                const int le = ch * 16 + half * 8 + u;
                int kxu = lane_bcast_i(kxv, le);
                st[u] = *(const unsigned*)(TTb2 + kxu);
            }
            PIPE_FENCE();
            #pragma unroll
            for (int u = 0; u < 8; ++u) {            // consume
                const int le = ch * 16 + half * 8 + u;
                const int e = half * 8 + u;
                float fu  = lane_bcast_f(ff, le);
                float fau = lane_bcast_f(fa, le);
                float fbu = lane_bcast_f(fb, le);
                float2 tt = pair2f(st[u]);
                float hv = fmaf(fu, tt.y - tt.x, tt.x);
                hv = fmaf(fau, wa, hv);
                hv = fmaf(fbu, wb, hv);
                sh[e * 65 + c] = fmaxf(hv, 0.0f);
            }
        }
        // lane = (khalf, edge, logit); half-k dot then combine
        float lsum = bias2;
        #pragma unroll 8
        for (int k8 = 0; k8 < 32; ++k8) {
            int k = kh * 32 + k8;
            lsum = fmaf(sh[e2 * 65 + k], s_w2[2 * k + p2], lsum);
        }
        lsum += __shfl_xor(lsum, 32, 64);
        float other = __shfl_xor(lsum, 1, 64);
        float m = fmaxf(lsum, other);
        float ea = __expf(lsum - m), eb = __expf(other - m);
        float r = ea / (ea + eb);
        if (c < 32) out[ebase * 2 + ch * 32 + c] = r;
    }
}

extern "C" void kernel_launch(void* const* d_in, const int* in_sizes, int n_in,
                              void* d_out, int out_size, void* d_ws, size_t ws_size,
                              hipStream_t stream) {
    const int*   types = (const int*)d_in[0];
    const float* dist  = (const float*)d_in[1];
    const float* emb   = (const float*)d_in[4];
    const float* w1    = (const float*)d_in[5];
    const float* pw1   = (const float*)d_in[6];
    const float* pb1   = (const float*)d_in[7];
    const float* pw2   = (const float*)d_in[8];
    const float* pb2   = (const float*)d_in[9];
    const float* qw1   = (const float*)d_in[10];
    const float* qb1   = (const float*)d_in[11];
    const float* qw2   = (const float*)d_in[12];
    const float* qb2   = (const float*)d_in[13];
    const float* auw1  = (const float*)d_in[14];
    const float* aub1  = (const float*)d_in[15];
    const float* auw2  = (const float*)d_in[16];
    const float* aub2  = (const float*)d_in[17];
    const float* row1  = (const float*)d_in[18];
    const float* rob1  = (const float*)d_in[19];
    const float* row2  = (const float*)d_in[20];
    const float* rob2  = (const float*)d_in[21];

    float* ws   = (float*)d_ws;
    float* outp = (float*)d_out;
    const __half2* TT = (const __half2*)(ws + WS_TT);
    __half* nwbuf[2] = { (__half*)(ws + WS_NWA), (__half*)(ws + WS_NWB) };

    k_pre<<<848, 256, 0, stream>>>(types, dist, emb, w1, pw1, pb1, pw2, pb2,
                                   row1, rob1, ws);
    for (int l = 0; l < 3; ++l) {
        k_edgeupd<<<768, 512, 0, stream>>>(TT + l * (G * DIM),
            ws + WS_DISTT, nwbuf[l & 1],
            qw1 + l * DIM * DIM, qb1 + l * DIM,
            qw2 + l * DIM * DIM, qb2 + l * DIM,
            ws + WS_H,
            (l < 2) ? (w1 + (l + 1) * DIM * DIM) : w1, nwbuf[(l + 1) & 1],
            auw1, aub1, auw2, aub2, ws + WS_HA, (l == 2) ? 1 : 0);
    }
    k_ro<<<2301, 256, 0, stream>>>(dist, ws + WS_HA, TT + 3 * (G * DIM),
                                   row1, row2, rob2, outp);
}

// Round 15
// 172.092 us; speedup vs baseline: 1.0130x; 1.0130x over previous
//
#include <hip/hip_runtime.h>
#include <hip/hip_fp16.h>

#define NATOMS 768
#define NM1    767
#define NEDGE  (768*767)       // 589056
#define DIM    64
#define NC     50
#define GAPF   (5.0f/49.0f)
#define NIGAP  (-49.0f/5.0f)
#define G      512
#define STEPF  (5.0f/511.0f)
#define INVSTEP (511.0f/5.0f)
#define LN2F   0.693147180559945f

// ws layout (float offsets)
#define WS_H     0              // 768*64 f32
#define WS_NWA   49152          // 768*64 f16 ROW-MAJOR: nw[i*64+c]
#define WS_NWB   73728          // 768*64 f16 row-major
#define WS_HA    98304          // 768 f32 (+pad)
#define WS_DISTT 99328          // 768*768 f32
#define WS_TT    689152         // 4 tables * 512*64 __half2 = 131072 float slots

#define PIPE_FENCE() asm volatile("" ::: "memory")

__device__ __forceinline__ float softplus05(float x) {
    float bx = 0.5f * x;
    return (bx > 14.0f) ? x : 2.0f * __logf(1.0f + __expf(bx));
}
__device__ __forceinline__ int lane_bcast_i(int v, int l) {
    return __builtin_amdgcn_readlane(v, l);
}
__device__ __forceinline__ float lane_bcast_f(float v, int l) {
    return __uint_as_float((unsigned)__builtin_amdgcn_readlane((int)__float_as_uint(v), l));
}
__device__ __forceinline__ float2 pair2f(unsigned p) {
    __half2 h = *reinterpret_cast<__half2*>(&p);
    return __half22float2(h);
}

// ============ prologue: f16 tables + embed/nw0(row-major f16) + dist transpose ====
__global__ __launch_bounds__(256)
void k_pre(const int* __restrict__ types, const float* __restrict__ dist,
           const float* __restrict__ emb, const float* __restrict__ w1all,
           const float* __restrict__ pw1, const float* __restrict__ pb1,
           const float* __restrict__ pw2, const float* __restrict__ pb2,
           const float* __restrict__ row1, const float* __restrict__ rob1,
           float* __restrict__ ws) {
    __shared__ float s_t[4 * 64];
    __shared__ float s_tile[64][65];
    const int tid = threadIdx.x, widx = tid >> 6, c = tid & 63;
    float*  h     = ws + WS_H;
    __half* nwh   = (__half*)(ws + WS_NWA);
    float*  distT = ws + WS_DISTT;
    __half* TTh   = (__half*)(ws + WS_TT);
    const int b = blockIdx.x;

    if (b < 512) {
        const int w = b * 4 + widx, tbl = w >> 9, g = w & 511;
        const float d = g * STEPF;
        float val;
        if (tbl < 3) {
            const float* W1 = pw1 + tbl * NC * DIM;
            float t1 = pb1[tbl * DIM + c];
            for (int k = 0; k < NC; ++k) {
                float x = d - GAPF * (float)k;
                t1 = fmaf(__expf(NIGAP * x * x), W1[k * DIM + c], t1);
            }
            s_t[widx * 64 + c] = softplus05(t1);     // wave-local lockstep
            const float* W2 = pw2 + tbl * DIM * DIM;
            val = pb2[tbl * DIM + c];
            #pragma unroll 8
            for (int k = 0; k < DIM; ++k)
                val = fmaf(s_t[widx * 64 + k], W2[k * DIM + c], val);
        } else {
            val = rob1[c];
            for (int k = 0; k < NC; ++k) {
                float x = d - GAPF * (float)k;
                val = fmaf(__expf(NIGAP * x * x), row1[(2 + k) * DIM + c], val);
            }
        }
        // paired f16 layout: entry (g,c) holds (T[g][c], T[g+1][c]) as __half2
        __half* TTt = TTh + tbl * (G * DIM * 2);
        TTt[(g * DIM + c) * 2] = __float2half(val);
        if (g > 0) TTt[((g - 1) * DIM + c) * 2 + 1] = __float2half(val);
    } else if (b < 704) {
        const int i = (b - 512) * 4 + widx;
        float hv = emb[types[i] * DIM + c];
        h[i * DIM + c] = hv;
        s_t[widx * 64 + c] = hv;                     // wave-local
        float acc = 0.0f;
        #pragma unroll 8
        for (int k = 0; k < DIM; ++k)
            acc = fmaf(s_t[widx * 64 + k], w1all[k * DIM + c], acc);
        nwh[i * 64 + c] = __float2half(acc);         // row-major
    } else {
        // ---- coalesced tiled transpose: dist(i-major, edge order) -> distT[j][i]
        const int t = b - 704;                       // 144 tiles = 12 x 12
        const int I0 = (t / 12) * 64, J0 = (t % 12) * 64;
        #pragma unroll 4
        for (int r = 0; r < 16; ++r) {               // read rows of dist, coalesced in j
            const int i = I0 + widx * 16 + r;
            const int j = J0 + c;
            s_tile[widx * 16 + r][c] =
                (i == j) ? 0.0f : dist[i * NM1 + (j - (j > i))];
        }
        __syncthreads();
        #pragma unroll 4
        for (int r = 0; r < 16; ++r) {               // write rows of distT, coalesced in i
            const int j = J0 + widx * 16 + r;
            const int i = I0 + c;
            distT[j * NATOMS + i] = s_tile[c][widx * 16 + r];
        }
    }
}

// ============ conv layer: R12 edge loop + PARALLEL-K tail across 8 waves =======
// 768 blocks x 8 waves; wave widx covers sources [widx*96, widx*96+96).
// Tail MLPs: wave widx computes k-slice [widx*8, widx*8+8) partials; wave 0
// combines.  (R13-proven: -8.3 us vs single-wave lockstep tail.)
__global__ __launch_bounds__(512)
void k_edgeupd(const __half2* __restrict__ TTl, const float* __restrict__ distT,
               const __half* __restrict__ nwin,
               const float* __restrict__ qw1, const float* __restrict__ qb1,
               const float* __restrict__ qw2, const float* __restrict__ qb2,
               float* __restrict__ h,
               const float* __restrict__ wnext, __half* __restrict__ nwout,
               const float* __restrict__ auw1, const float* __restrict__ aub1,
               const float* __restrict__ auw2, const float* __restrict__ aub2,
               float* __restrict__ ha, int last) {
    __shared__ float s_part[8][64];                  // edge partials, then k-partials
    __shared__ float s_upd[192];
    const int tid = threadIdx.x, widx = tid >> 6, c = tid & 63;
    const int j = blockIdx.x;
    const int s0 = widx * 96;
    const int half = c >> 5, cl = c & 31;

    // prefetch wave-0 tail operands early (uniform across waves, L1 broadcast)
    float2 t0_pf = pair2f(((const unsigned*)TTl)[c]);
    float nwj_pf = __half2float(nwin[j * 64 + c]);
    float hj_pf  = h[j * DIM + c];

    const char* TTrow = (const char*)TTl + cl * 8;   // lane's 2-channel slot in a row
    float2 csum = make_float2(0.0f, 0.0f);
    { // ---- chunk A: sources s0 .. s0+63 (32 pairs); lane c holds (g,f) of s0+c
        float d = distT[j * NATOMS + s0 + c];
        float pos = d * INVSTEP;
        int g = (int)pos;
        g = (g < 0) ? 0 : ((g > 510) ? 510 : g);
        float f = pos - (float)g;
        int kx = g * 256;                            // byte offset of f16 row
        const char* nwrow = (const char*)nwin + s0 * 128 + half * 128 + cl * 4;
        for (int grp = 0; grp < 4; ++grp) {          // 4 groups of 8 pairs
            uint2 st[8]; unsigned sn[8];
            #pragma unroll
            for (int u = 0; u < 8; ++u) {            // stage: 16 independent loads
                const int t = grp * 8 + u;
                int kx0 = lane_bcast_i(kx, 2 * t);
                int kx1 = lane_bcast_i(kx, 2 * t + 1);
                int kxs = half ? kx1 : kx0;
                st[u] = *(const uint2*)(TTrow + kxs);
                sn[u] = *(const unsigned*)(nwrow + t * 256);
            }
            PIPE_FENCE();
            #pragma unroll
            for (int u = 0; u < 8; ++u) {            // consume
                const int t = grp * 8 + u;
                float f0 = lane_bcast_f(f, 2 * t);
                float f1 = lane_bcast_f(f, 2 * t + 1);
                float fs = half ? f1 : f0;
                float2 ta = pair2f(st[u].x);
                float2 tb = pair2f(st[u].y);
                float2 nwf = pair2f(sn[u]);
                float e0 = fmaf(fs, ta.y - ta.x, ta.x);
                float e1 = fmaf(fs, tb.y - tb.x, tb.x);
                csum.x = fmaf(e0, nwf.x, csum.x);
                csum.y = fmaf(e1, nwf.y, csum.y);
            }
        }
    }
    { // ---- chunk B: sources s0+64 .. s0+95 (16 pairs); lanes mirrored via c&31
        float d = distT[j * NATOMS + s0 + 64 + cl];
        float pos = d * INVSTEP;
        int g = (int)pos;
        g = (g < 0) ? 0 : ((g > 510) ? 510 : g);
        float f = pos - (float)g;
        int kx = g * 256;
        const char* nwrow = (const char*)nwin + (s0 + 64) * 128 + half * 128 + cl * 4;
        for (int grp = 0; grp < 2; ++grp) {          // 2 groups of 8 pairs
            uint2 st[8]; unsigned sn[8];
            #pragma unroll
            for (int u = 0; u < 8; ++u) {
                const int t = grp * 8 + u;
                int kx0 = lane_bcast_i(kx, 2 * t);
                int kx1 = lane_bcast_i(kx, 2 * t + 1);
                int kxs = half ? kx1 : kx0;
                st[u] = *(const uint2*)(TTrow + kxs);
                sn[u] = *(const unsigned*)(nwrow + t * 256);
            }
            PIPE_FENCE();
            #pragma unroll
            for (int u = 0; u < 8; ++u) {
                const int t = grp * 8 + u;
                float f0 = lane_bcast_f(f, 2 * t);
                float f1 = lane_bcast_f(f, 2 * t + 1);
                float fs = half ? f1 : f0;
                float2 ta = pair2f(st[u].x);
                float2 tb = pair2f(st[u].y);
                float2 nwf = pair2f(sn[u]);
                float e0 = fmaf(fs, ta.y - ta.x, ta.x);
                float e1 = fmaf(fs, tb.y - tb.x, tb.x);
                csum.x = fmaf(e0, nwf.x, csum.x);
                csum.y = fmaf(e1, nwf.y, csum.y);
            }
        }
    }
    // combine even/odd source halves and repack to channel-per-slot
    float2 tot2;
    tot2.x = csum.x + __shfl_xor(csum.x, 32, 64);
    tot2.y = csum.y + __shfl_xor(csum.y, 32, 64);
    if (half == 0) *(float2*)&s_part[widx][2 * cl] = tot2;
    __syncthreads();

    // ---- stage A: combine edge partials + diag fix (wave 0) -> s_upd[0..63]
    if (widx == 0) {
        float tot = 0.0f;
        #pragma unroll
        for (int w8 = 0; w8 < 8; ++w8) tot += s_part[w8][c];
        tot -= t0_pf.x * nwj_pf;     // remove fake i==j term (e = T[0][c] exactly)
        s_upd[c] = tot;
    }
    __syncthreads();
    // ---- stage B: MLP1 parallel-k (all 8 waves), combine + softplus (wave 0)
    {
        const int k0 = widx * 8;
        float p = 0.0f;
        #pragma unroll
        for (int u = 0; u < 8; ++u)
            p = fmaf(s_upd[k0 + u], qw1[(k0 + u) * DIM + c], p);
        s_part[widx][c] = p;
    }
    __syncthreads();
    if (widx == 0) {
        float t = qb1[c];
        #pragma unroll
        for (int w8 = 0; w8 < 8; ++w8) t += s_part[w8][c];
        s_upd[64 + c] = softplus05(t);
    }
    __syncthreads();
    // ---- stage C: MLP2 parallel-k, combine + h update (wave 0)
    {
        const int k0 = widx * 8;
        float p = 0.0f;
        #pragma unroll
        for (int u = 0; u < 8; ++u)
            p = fmaf(s_upd[64 + k0 + u], qw2[(k0 + u) * DIM + c], p);
        s_part[widx][c] = p;
    }
    __syncthreads();
    if (widx == 0) {
        float o = qb2[c];
        #pragma unroll
        for (int w8 = 0; w8 < 8; ++w8) o += s_part[w8][c];
        float hn = hj_pf + o;
        h[j * DIM + c] = hn;
        s_upd[128 + c] = hn;
    }
    __syncthreads();
    // ---- stage D: next-layer nw (or atom-update head) parallel-k
    {
        const int k0 = widx * 8;
        const float* W = last ? auw1 : wnext;
        float p = 0.0f;
        #pragma unroll
        for (int u = 0; u < 8; ++u)
            p = fmaf(s_upd[128 + k0 + u], W[(k0 + u) * DIM + c], p);
        s_part[widx][c] = p;
    }
    __syncthreads();
    if (widx == 0) {
        if (!last) {
            float v = 0.0f;
            #pragma unroll
            for (int w8 = 0; w8 < 8; ++w8) v += s_part[w8][c];
            nwout[j * 64 + c] = __float2half(v);     // row-major
        } else {
            float t2 = aub1[c];
            #pragma unroll
            for (int w8 = 0; w8 < 8; ++w8) t2 += s_part[w8][c];
            t2 = ((t2 > 20.0f) ? t2 : __logf(1.0f + __expf(t2))) - LN2F;
            float v = t2 * auw2[c];
            #pragma unroll
            for (int s = 32; s > 0; s >>= 1) v += __shfl_down(v, s, 64);
            if (c == 0) ha[j] = v + aub2[0];
        }
    }
}

// ============ readout: FENCED staged loads; src/dst by exact magic division ====
__global__ __launch_bounds__(256)
void k_ro(const float* __restrict__ dist, const float* __restrict__ ha,
          const __half2* __restrict__ TTro,
          const float* __restrict__ row1, const float* __restrict__ row2,
          const float* __restrict__ rob2, float* __restrict__ out) {
    __shared__ float s_h[4][16 * 65];
    __shared__ float s_w2[128];
    const int tid = threadIdx.x, widx = tid >> 6, c = tid & 63;
    if (tid < 128) s_w2[tid] = row2[tid];
    __syncthreads();
    const int ebase = (blockIdx.x * 4 + widx) * 64;

    // lane c holds the params of edge ebase+c, in registers
    int kxv; float ff, fa, fb;
    {
        int eg = ebase + c;
        float d = dist[eg];
        float pos = d * INVSTEP;
        int kk = (int)pos;
        kk = (kk < 0) ? 0 : ((kk > 510) ? 510 : kk);
        kxv = kk * 256;
        ff = pos - (float)kk;
        // src = eg/767 (exact magic div), dst = r + (r>=src)
        unsigned i = (unsigned)(((unsigned long long)(unsigned)eg * 2867044662ull) >> 41);
        int r = eg - (int)i * 767;
        int jd = r + (r >= (int)i);
        fa = ha[i];
        fb = ha[jd];
    }
    const char* TTb2 = (const char*)TTro + c * 4;
    const float wa = row1[c], wb = row1[DIM + c];
    const int e2 = (c >> 1) & 15, p2 = c & 1, kh = c >> 5;
    const float bias2 = (kh == 0) ? rob2[p2] : 0.0f;
    float* sh = s_h[widx];
    #pragma unroll
    for (int ch = 0; ch < 4; ++ch) {
        #pragma unroll
        for (int half = 0; half < 2; ++half) {
            unsigned st[8];
            #pragma unroll
            for (int u = 0; u < 8; ++u) {            // stage: 8 independent row loads
                const int le = ch * 16 + half * 8 + u;
                int kxu = lane_bcast_i(kxv, le);
                st[u] = *(const unsigned*)(TTb2 + kxu);
            }
            PIPE_FENCE();
            #pragma unroll
            for (int u = 0; u < 8; ++u) {            // consume
                const int le = ch * 16 + half * 8 + u;
                const int e = half * 8 + u;
                float fu  = lane_bcast_f(ff, le);
                float fau = lane_bcast_f(fa, le);
                float fbu = lane_bcast_f(fb, le);
                float2 tt = pair2f(st[u]);
                float hv = fmaf(fu, tt.y - tt.x, tt.x);
                hv = fmaf(fau, wa, hv);
                hv = fmaf(fbu, wb, hv);
                sh[e * 65 + c] = fmaxf(hv, 0.0f);
            }
        }
        // lane = (khalf, edge, logit); half-k dot then combine
        float lsum = bias2;
        #pragma unroll 8
        for (int k8 = 0; k8 < 32; ++k8) {
            int k = kh * 32 + k8;
            lsum = fmaf(sh[e2 * 65 + k], s_w2[2 * k + p2], lsum);
        }
        lsum += __shfl_xor(lsum, 32, 64);
        float other = __shfl_xor(lsum, 1, 64);
        float m = fmaxf(lsum, other);
        float ea = __expf(lsum - m), eb = __expf(other - m);
        float r = ea / (ea + eb);
        if (c < 32) out[ebase * 2 + ch * 32 + c] = r;
    }
}

extern "C" void kernel_launch(void* const* d_in, const int* in_sizes, int n_in,
                              void* d_out, int out_size, void* d_ws, size_t ws_size,
                              hipStream_t stream) {
    const int*   types = (const int*)d_in[0];
    const float* dist  = (const float*)d_in[1];
    const float* emb   = (const float*)d_in[4];
    const float* w1    = (const float*)d_in[5];
    const float* pw1   = (const float*)d_in[6];
    const float* pb1   = (const float*)d_in[7];
    const float* pw2   = (const float*)d_in[8];
    const float* pb2   = (const float*)d_in[9];
    const float* qw1   = (const float*)d_in[10];
    const float* qb1   = (const float*)d_in[11];
    const float* qw2   = (const float*)d_in[12];
    const float* qb2   = (const float*)d_in[13];
    const float* auw1  = (const float*)d_in[14];
    const float* aub1  = (const float*)d_in[15];
    const float* auw2  = (const float*)d_in[16];
    const float* aub2  = (const float*)d_in[17];
    const float* row1  = (const float*)d_in[18];
    const float* rob1  = (const float*)d_in[19];
    const float* row2  = (const float*)d_in[20];
    const float* rob2  = (const float*)d_in[21];

    float* ws   = (float*)d_ws;
    float* outp = (float*)d_out;
    const __half2* TT = (const __half2*)(ws + WS_TT);
    __half* nwbuf[2] = { (__half*)(ws + WS_NWA), (__half*)(ws + WS_NWB) };

    k_pre<<<848, 256, 0, stream>>>(types, dist, emb, w1, pw1, pb1, pw2, pb2,
                                   row1, rob1, ws);
    for (int l = 0; l < 3; ++l) {
        k_edgeupd<<<768, 512, 0, stream>>>(TT + l * (G * DIM),
            ws + WS_DISTT, nwbuf[l & 1],
            qw1 + l * DIM * DIM, qb1 + l * DIM,
            qw2 + l * DIM * DIM, qb2 + l * DIM,
            ws + WS_H,
            (l < 2) ? (w1 + (l + 1) * DIM * DIM) : w1, nwbuf[(l + 1) & 1],
            auw1, aub1, auw2, aub2, ws + WS_HA, (l == 2) ? 1 : 0);
    }
    k_ro<<<2301, 256, 0, stream>>>(dist, ws + WS_HA, TT + 3 * (G * DIM),
                                   row1, row2, rob2, outp);
}